// Round 1
// baseline (875.105 us; speedup 1.0000x reference)
//
#include <hip/hip_runtime.h>

constexpr int N_NODES = 50000;
constexpr int N_EDGES = 800000;
constexpr int IN_DIM  = 128;
constexpr int HD      = 128;
constexpr int NREL    = 8;

// ---------------- utility ----------------
__global__ void k_zero_i32(int* __restrict__ p, int n){
  int i = blockIdx.x*blockDim.x + threadIdx.x;
  if(i<n) p[i]=0;
}

// ---------------- CSR build ----------------
__global__ void k_hist(const int* __restrict__ dst, int* __restrict__ deg){
  int i = blockIdx.x*blockDim.x + threadIdx.x;
  if(i<N_EDGES) atomicAdd(&deg[dst[i]],1);
}

__global__ void k_scan1(const int* __restrict__ in, int* __restrict__ out,
                        int* __restrict__ part, int n){
  __shared__ int sm[256];
  int t = threadIdx.x; int i = blockIdx.x*256+t;
  int v = (i<n)? in[i] : 0;
  sm[t]=v; __syncthreads();
  for(int off=1; off<256; off<<=1){
    int x = (t>=off)? sm[t-off] : 0;
    __syncthreads();
    sm[t]+=x;
    __syncthreads();
  }
  if(i<n) out[i]=sm[t]-v;       // exclusive scan within block
  if(t==255) part[blockIdx.x]=sm[255];
}

__global__ void k_scan2(int* __restrict__ part, int nb){
  __shared__ int sm[256];
  int t=threadIdx.x;
  int v=(t<nb)? part[t] : 0;
  sm[t]=v; __syncthreads();
  for(int off=1; off<256; off<<=1){
    int x=(t>=off)? sm[t-off]:0;
    __syncthreads();
    sm[t]+=x;
    __syncthreads();
  }
  if(t<nb) part[t]=sm[t]-v;     // exclusive block offsets
}

__global__ void k_scan3(int* __restrict__ out, const int* __restrict__ part, int n){
  int i = blockIdx.x*blockDim.x+threadIdx.x;
  if(i<n) out[i]+=part[blockIdx.x];
}

__global__ void k_scatter(const int* __restrict__ src, const int* __restrict__ et,
                          const float* __restrict__ w, const int* __restrict__ dst,
                          const int* __restrict__ offs, int* __restrict__ cur,
                          int* __restrict__ src_s, int* __restrict__ et_s,
                          float* __restrict__ w_s){
  int i = blockIdx.x*blockDim.x + threadIdx.x;
  if(i<N_EDGES){
    int d=dst[i];
    int pos=offs[d]+atomicAdd(&cur[d],1);
    src_s[pos]=src[i]; et_s[pos]=et[i]; w_s[pos]=w[i];
  }
}

// ---------------- relation-combined weights: W[r,i,o] = sum_b comp[r,b] V[b,i,o]
__global__ void k_relw(const float* __restrict__ comp, const float* __restrict__ V,
                       float* __restrict__ W){
  int idx = blockIdx.x*blockDim.x + threadIdx.x;
  if(idx < NREL*IN_DIM*HD){
    int r  = idx >> 14;       // /(128*128)
    int io = idx & 16383;
    float s=0.f;
    #pragma unroll
    for(int b=0;b<NREL;b++) s += comp[r*NREL+b]*V[(b<<14)+io];
    W[idx]=s;
  }
}

// ---------------- H = X @ W  (per relation chunk). 64x64 tile, 4x4/thread.
__global__ void __launch_bounds__(256)
k_gemm(const float* __restrict__ X, const float* __restrict__ W,
       float* __restrict__ H, int ncol){
  __shared__ float As[8][65];
  __shared__ float Bs[8][65];
  int tid = threadIdx.x;
  int tc = tid & 15, tr = tid >> 4;
  int col0 = blockIdx.x*64;
  int row0 = blockIdx.y*64;
  int r  = col0 >> 7;         // relation within chunk (64 | 128 so constant per block)
  int o0 = col0 & 127;
  const float* Wb = W + (size_t)r*IN_DIM*HD + o0;
  float acc[4][4]={};
  for(int k0=0;k0<IN_DIM;k0+=8){
    #pragma unroll
    for(int q=0;q<2;q++){
      int e = tid + q*256;
      int rr = e>>3, kk = e&7;
      int grow = row0+rr;
      As[kk][rr] = (grow<N_NODES) ? X[(size_t)grow*IN_DIM + k0 + kk] : 0.f;
    }
    #pragma unroll
    for(int q=0;q<2;q++){
      int e = tid + q*256;
      int kk = e>>6, cc = e&63;
      Bs[kk][cc] = Wb[(size_t)(k0+kk)*HD + cc];
    }
    __syncthreads();
    #pragma unroll
    for(int kk=0;kk<8;kk++){
      float a[4], b[4];
      #pragma unroll
      for(int m=0;m<4;m++) a[m]=As[kk][tr*4+m];
      #pragma unroll
      for(int n2=0;n2<4;n2++) b[n2]=Bs[kk][tc*4+n2];
      #pragma unroll
      for(int m=0;m<4;m++)
        #pragma unroll
        for(int n2=0;n2<4;n2++) acc[m][n2] += a[m]*b[n2];
    }
    __syncthreads();
  }
  #pragma unroll
  for(int m=0;m<4;m++){
    int grow=row0+tr*4+m;
    if(grow<N_NODES){
      float* Hp=&H[(size_t)grow*ncol + col0 + tc*4];
      Hp[0]=acc[m][0]; Hp[1]=acc[m][1]; Hp[2]=acc[m][2]; Hp[3]=acc[m][3];
    }
  }
}

// ---------------- per-dst aggregation over CSR edges ----------------
// flags: 1=first chunk (overwrite), 2=last chunk (bias), 4=relu
__global__ void k_agg(const float* __restrict__ H, const int* __restrict__ offs,
                      const int* __restrict__ deg, const int* __restrict__ src_s,
                      const int* __restrict__ et_s, const float* __restrict__ w_s,
                      const float* __restrict__ bias, float* __restrict__ out,
                      int rchunk, int r0, int flags){
  int n = blockIdx.x;
  int t = threadIdx.x;           // 0..127
  int beg = offs[n];
  int cnt = deg[n];
  int stride = rchunk*HD;
  float acc=0.f;
  for(int j=0;j<cnt;j++){
    int e=beg+j;
    int et=et_s[e];
    if((unsigned)(et-r0) < (unsigned)rchunk){
      acc += w_s[e]*H[(size_t)src_s[e]*stride + (size_t)(et-r0)*HD + t];
    }
  }
  float v = (flags&1)? acc : out[(size_t)n*HD+t]+acc;
  if(flags&2){ v += bias[t]; if(flags&4) v=fmaxf(v,0.f); }
  out[(size_t)n*HD+t]=v;
}

extern "C" void kernel_launch(void* const* d_in, const int* in_sizes, int n_in,
                              void* d_out, int out_size, void* d_ws, size_t ws_size,
                              hipStream_t stream){
  const float* feat  = (const float*)d_in[0];
  const int*   etyp  = (const int*)  d_in[1];
  const float* ew    = (const float*)d_in[2];
  const int*   src   = (const int*)  d_in[3];
  const int*   dst   = (const int*)  d_in[4];
  const float* comp1 = (const float*)d_in[5];
  const float* V1    = (const float*)d_in[6];
  const float* bias1 = (const float*)d_in[7];
  const float* comp2 = (const float*)d_in[8];
  const float* V2    = (const float*)d_in[9];
  const float* bias2 = (const float*)d_in[10];
  float* out = (float*)d_out;

  char* p = (char*)d_ws;
  auto alloc = [&](size_t bytes)->char* {
    char* q = p; p += (bytes + 255) & ~(size_t)255; return q;
  };
  float* Wbuf  = (float*)alloc((size_t)NREL*IN_DIM*HD*4);
  float* hmid  = (float*)alloc((size_t)N_NODES*HD*4);
  int*   deg   = (int*)  alloc((size_t)N_NODES*4);
  int*   offs  = (int*)  alloc((size_t)N_NODES*4);
  int*   cur   = (int*)  alloc((size_t)N_NODES*4);
  int*   part  = (int*)  alloc(256*4);
  int*   src_s = (int*)  alloc((size_t)N_EDGES*4);
  int*   et_s  = (int*)  alloc((size_t)N_EDGES*4);
  float* w_s   = (float*)alloc((size_t)N_EDGES*4);
  size_t used  = (size_t)(p-(char*)d_ws);
  size_t perRel = (size_t)N_NODES*HD*4;
  int C = 1;
  if (ws_size > used) {
    size_t avail = ws_size - used;
    size_t c = avail / perRel;
    C = (c > 8) ? 8 : (c < 1 ? 1 : (int)c);
  }
  float* Hbuf = (float*)alloc(perRel*(size_t)C);

  // ---- CSR build (once, shared by both layers) ----
  k_zero_i32<<<(N_NODES+255)/256,256,0,stream>>>(deg,N_NODES);
  k_zero_i32<<<(N_NODES+255)/256,256,0,stream>>>(cur,N_NODES);
  k_hist<<<(N_EDGES+255)/256,256,0,stream>>>(dst,deg);
  int nb=(N_NODES+255)/256; // 196
  k_scan1<<<nb,256,0,stream>>>(deg,offs,part,N_NODES);
  k_scan2<<<1,256,0,stream>>>(part,nb);
  k_scan3<<<nb,256,0,stream>>>(offs,part,N_NODES);
  k_scatter<<<(N_EDGES+255)/256,256,0,stream>>>(src,etyp,ew,dst,offs,cur,src_s,et_s,w_s);

  // ---- two RGCN layers ----
  for(int layer=0; layer<2; ++layer){
    const float* comp = layer? comp2 : comp1;
    const float* V    = layer? V2    : V1;
    const float* bias = layer? bias2 : bias1;
    const float* X    = layer? hmid  : feat;
    float*       O    = layer? out   : hmid;
    int relu          = layer? 0     : 4;

    k_relw<<<(NREL*IN_DIM*HD+255)/256,256,0,stream>>>(comp,V,Wbuf);

    int nchunks = (NREL + C - 1)/C;
    for(int c=0;c<nchunks;c++){
      int r0 = c*C;
      int rc = (NREL - r0 < C) ? (NREL - r0) : C;
      dim3 g(rc*2, (N_NODES+63)/64);
      k_gemm<<<g,256,0,stream>>>(X, Wbuf + (size_t)r0*IN_DIM*HD, Hbuf, rc*HD);
      int flags = (c==0?1:0) | (c==nchunks-1 ? 2 : 0) | (c==nchunks-1 ? relu : 0);
      k_agg<<<N_NODES,128,0,stream>>>(Hbuf,offs,deg,src_s,et_s,w_s,bias,O,rc,r0,flags);
    }
  }
}

// Round 2
// 390.955 us; speedup vs baseline: 2.2384x; 2.2384x over previous
//
#include <hip/hip_runtime.h>
#include <stdint.h>

constexpr int N_NODES = 50000;
constexpr int N_EDGES = 800000;
constexpr int HD      = 128;
constexpr int NREL    = 8;
constexpr int NBUCK   = N_NODES * NREL;   // 400000 (dst,etype) buckets

typedef unsigned short ushortT;
using bf16x8 = __attribute__((ext_vector_type(8))) short;
using f32x4  = __attribute__((ext_vector_type(4))) float;

__device__ __forceinline__ float b2f(uint32_t lo16){
  uint32_t x = lo16 << 16; float f; __builtin_memcpy(&f,&x,4); return f;
}
__device__ __forceinline__ uint16_t f2b(float f){
  uint32_t x; __builtin_memcpy(&x,&f,4);
  uint32_t r = (x + 0x7FFFu + ((x>>16)&1u)) >> 16;
  return (uint16_t)r;
}

// ---------------- utility ----------------
__global__ void k_zero_i32(int* __restrict__ p, int n){
  int i = blockIdx.x*blockDim.x + threadIdx.x;
  if(i<n) p[i]=0;
}

// ---------------- CSR build over (dst*8+etype) buckets ----------------
__global__ void k_hist(const int* __restrict__ dst, const int* __restrict__ et,
                       int* __restrict__ deg){
  int i = blockIdx.x*blockDim.x + threadIdx.x;
  if(i<N_EDGES) atomicAdd(&deg[dst[i]*NREL + et[i]],1);
}

__global__ void k_scan1(const int* __restrict__ in, int* __restrict__ out,
                        int* __restrict__ part, int n){
  __shared__ int sm[256];
  int t = threadIdx.x; int i = blockIdx.x*256+t;
  int v = (i<n)? in[i] : 0;
  sm[t]=v; __syncthreads();
  for(int off=1; off<256; off<<=1){
    int x = (t>=off)? sm[t-off] : 0;
    __syncthreads();
    sm[t]+=x;
    __syncthreads();
  }
  if(i<n) out[i]=sm[t]-v;       // exclusive within block
  if(t==255) part[blockIdx.x]=sm[255];
}

__global__ void k_scan2(int* __restrict__ part, int nb){
  __shared__ int sm[256];
  int t=threadIdx.x;
  int v=(t<nb)? part[t] : 0;
  sm[t]=v; __syncthreads();
  for(int off=1; off<256; off<<=1){
    int x=(t>=off)? sm[t-off]:0;
    __syncthreads();
    sm[t]+=x;
    __syncthreads();
  }
  if(t<nb) part[t]=sm[t]-v;
}

__global__ void k_scan3(int* __restrict__ out, const int* __restrict__ part, int n){
  int i = blockIdx.x*blockDim.x+threadIdx.x;
  if(i<n) out[i]+=part[blockIdx.x];
}

__global__ void k_scatter(const int* __restrict__ src, const int* __restrict__ et,
                          const float* __restrict__ w, const int* __restrict__ dst,
                          const int* __restrict__ offs, int* __restrict__ cur,
                          int* __restrict__ src_s, float* __restrict__ w_s){
  int i = blockIdx.x*blockDim.x + threadIdx.x;
  if(i<N_EDGES){
    int b = dst[i]*NREL + et[i];
    int pos = offs[b] + atomicAdd(&cur[b],1);
    src_s[pos]=src[i]; w_s[pos]=w[i];
  }
}

// ---------------- f32 -> bf16 table convert ----------------
__global__ void k_f2b(const float* __restrict__ in, ushortT* __restrict__ out, int n4){
  int i = blockIdx.x*blockDim.x + threadIdx.x;
  if(i<n4){
    float4 v = ((const float4*)in)[i];
    ushort4 o;
    o.x=f2b(v.x); o.y=f2b(v.y); o.z=f2b(v.z); o.w=f2b(v.w);
    ((ushort4*)out)[i]=o;
  }
}

// ---------------- Wt[o][r*128+k] = sum_b comp[r,b] V[b,k,o]  (B^T, bf16) ----
__global__ void k_relw(const float* __restrict__ comp, const float* __restrict__ V,
                       ushortT* __restrict__ Wt){
  int t = blockIdx.x*blockDim.x + threadIdx.x;
  if(t >= HD*NREL*HD) return;      // 131072
  int o  = t >> 10;                // 0..127
  int rk = t & 1023;
  int r  = rk >> 7, k = rk & 127;
  float s=0.f;
  #pragma unroll
  for(int b=0;b<NREL;b++) s += comp[r*NREL+b]*V[(b<<14) + k*HD + o];
  Wt[t]=f2b(s);
}

// ---------------- aggregate-first: Acat[n][r*128+k] (bf16) ----------------
// one wave per node; per relation: accumulate run in 2 regs, write 128 bf16
__global__ void __launch_bounds__(256)
k_agg(const ushortT* __restrict__ xb,   // [N][128] bf16 gather table
      const int* __restrict__ offs, const int* __restrict__ deg,
      const int* __restrict__ src_s, const float* __restrict__ w_s,
      ushortT* __restrict__ Acat){
  int node = blockIdx.x*4 + (threadIdx.x>>6);
  int lane = threadIdx.x & 63;
  if(node >= N_NODES) return;
  #pragma unroll
  for(int r=0;r<NREL;r++){
    int b = node*NREL + r;
    int beg = offs[b], cnt = deg[b];
    float a0=0.f, a1=0.f;
    for(int j=0;j<cnt;j++){
      int s   = src_s[beg+j];
      float w = w_s[beg+j];
      uint32_t u = *(const uint32_t*)&xb[(size_t)s*HD + lane*2];
      a0 += w * b2f(u & 0xFFFFu);
      a1 += w * b2f(u >> 16);
    }
    uint32_t pk = (uint32_t)f2b(a0) | ((uint32_t)f2b(a1)<<16);
    *(uint32_t*)&Acat[(size_t)b*HD + lane*2] = pk;
  }
}

// ---------------- MFMA GEMM: out[M][128] = Acat[M][1024] @ Wt^T ----------------
constexpr int BM=64, BN=128, BK=64, LDK=72;   // LDK pad: 144B row = 9x16B, bank shift 4
__global__ void __launch_bounds__(256)
k_gemm(const ushortT* __restrict__ A,   // [M][1024] bf16
       const ushortT* __restrict__ Wt,  // [128][1024] bf16 (B transposed)
       const float* __restrict__ bias,
       float* __restrict__ outF,        // layer2 output (f32) or null
       ushortT* __restrict__ outB,      // layer1 output (bf16) or null
       int M, int relu){
  __shared__ ushortT Asm[BM][LDK];
  __shared__ ushortT Bsm[BN][LDK];
  int tid = threadIdx.x;
  int wid = tid>>6, lane = tid&63;
  int l15 = lane&15, lhi = lane>>4;        // lhi 0..3
  int row0 = blockIdx.x*BM;
  int wr = (wid>>1)*32, wc = (wid&1)*64;   // wave tile 32x64
  f32x4 acc[2][4] = {};
  for(int kt=0; kt<NREL*HD; kt+=BK){
    // stage A: 64 rows x 64 k, 2 rounds of 256 lanes x 16B
    #pragma unroll
    for(int q=0;q<2;q++){
      int slot = q*256 + tid;
      int r = slot>>3, kb8 = (slot&7)*8;
      int grow = row0 + r; if(grow >= M) grow = M-1;
      *(bf16x8*)&Asm[r][kb8] = *(const bf16x8*)&A[(size_t)grow*1024 + kt + kb8];
    }
    // stage B: 128 cols x 64 k, 4 rounds
    #pragma unroll
    for(int q=0;q<4;q++){
      int slot = q*256 + tid;
      int c = slot>>3, kb8 = (slot&7)*8;
      *(bf16x8*)&Bsm[c][kb8] = *(const bf16x8*)&Wt[(size_t)c*1024 + kt + kb8];
    }
    __syncthreads();
    #pragma unroll
    for(int kk=0;kk<2;kk++){
      bf16x8 af[2], bfr[4];
      #pragma unroll
      for(int m=0;m<2;m++)  af[m]  = *(const bf16x8*)&Asm[wr + m*16 + l15][kk*32 + lhi*8];
      #pragma unroll
      for(int n=0;n<4;n++)  bfr[n] = *(const bf16x8*)&Bsm[wc + n*16 + l15][kk*32 + lhi*8];
      #pragma unroll
      for(int m=0;m<2;m++)
        #pragma unroll
        for(int n=0;n<4;n++)
          acc[m][n] = __builtin_amdgcn_mfma_f32_16x16x32_bf16(af[m], bfr[n], acc[m][n], 0,0,0);
    }
    __syncthreads();
  }
  // epilogue: D row=(lane>>4)*4+j, col=lane&15 per fragment
  #pragma unroll
  for(int m=0;m<2;m++){
    #pragma unroll
    for(int j=0;j<4;j++){
      int grow = row0 + wr + m*16 + lhi*4 + j;
      if(grow < M){
        #pragma unroll
        for(int n=0;n<4;n++){
          int col = wc + n*16 + l15;
          float v = acc[m][n][j] + bias[col];
          if(relu) v = fmaxf(v, 0.f);
          if(outF) outF[(size_t)grow*HD + col] = v;
          else     outB[(size_t)grow*HD + col] = f2b(v);
        }
      }
    }
  }
}

extern "C" void kernel_launch(void* const* d_in, const int* in_sizes, int n_in,
                              void* d_out, int out_size, void* d_ws, size_t ws_size,
                              hipStream_t stream){
  const float* feat  = (const float*)d_in[0];
  const int*   etyp  = (const int*)  d_in[1];
  const float* ew    = (const float*)d_in[2];
  const int*   src   = (const int*)  d_in[3];
  const int*   dst   = (const int*)  d_in[4];
  const float* comp1 = (const float*)d_in[5];
  const float* V1    = (const float*)d_in[6];
  const float* bias1 = (const float*)d_in[7];
  const float* comp2 = (const float*)d_in[8];
  const float* V2    = (const float*)d_in[9];
  const float* bias2 = (const float*)d_in[10];
  float* out = (float*)d_out;

  char* p = (char*)d_ws;
  auto alloc = [&](size_t bytes)->char* {
    char* q = p; p += (bytes + 255) & ~(size_t)255; return q;
  };
  ushortT* Wt    = (ushortT*)alloc((size_t)HD*NREL*HD*2);        // 256 KB
  ushortT* Acat  = (ushortT*)alloc((size_t)N_NODES*NREL*HD*2);   // 102.4 MB
  ushortT* xb    = (ushortT*)alloc((size_t)N_NODES*HD*2);        // 12.8 MB
  ushortT* hmid  = (ushortT*)alloc((size_t)N_NODES*HD*2);        // 12.8 MB
  int*   deg   = (int*)  alloc((size_t)NBUCK*4);
  int*   offs  = (int*)  alloc((size_t)NBUCK*4);
  int*   cur   = (int*)  alloc((size_t)NBUCK*4);
  int*   part1 = (int*)  alloc(2048*4);
  int*   part2 = (int*)  alloc(256*4);
  int*   src_s = (int*)  alloc((size_t)N_EDGES*4);
  float* w_s   = (float*)alloc((size_t)N_EDGES*4);

  // ---- CSR build over 400k (dst,etype) buckets ----
  int zb = (NBUCK+255)/256;           // 1563
  k_zero_i32<<<zb,256,0,stream>>>(deg,NBUCK);
  k_zero_i32<<<zb,256,0,stream>>>(cur,NBUCK);
  k_hist<<<(N_EDGES+255)/256,256,0,stream>>>(dst,etyp,deg);
  int nb1 = (NBUCK+255)/256;          // 1563
  int nb2 = (nb1+255)/256;            // 7
  k_scan1<<<nb1,256,0,stream>>>(deg,offs,part1,NBUCK);
  k_scan1<<<nb2,256,0,stream>>>(part1,part1,part2,nb1);   // in-place ok (read-before-write per thread)
  k_scan2<<<1,256,0,stream>>>(part2,nb2);
  k_scan3<<<nb2,256,0,stream>>>(part1,part2,nb1);
  k_scan3<<<nb1,256,0,stream>>>(offs,part1,NBUCK);
  k_scatter<<<(N_EDGES+255)/256,256,0,stream>>>(src,etyp,ew,dst,offs,cur,src_s,w_s);

  // ---- feature table to bf16 ----
  int n4 = N_NODES*HD/4;
  k_f2b<<<(n4+255)/256,256,0,stream>>>(feat, xb, n4);

  int gemmGrid = (N_NODES + BM - 1)/BM;   // 782
  // ---- layer 1 ----
  k_relw<<<(HD*NREL*HD+255)/256,256,0,stream>>>(comp1, V1, Wt);
  k_agg<<<N_NODES/4,256,0,stream>>>(xb, offs, deg, src_s, w_s, Acat);
  k_gemm<<<gemmGrid,256,0,stream>>>(Acat, Wt, bias1, nullptr, hmid, N_NODES, 1);
  // ---- layer 2 ----
  k_relw<<<(HD*NREL*HD+255)/256,256,0,stream>>>(comp2, V2, Wt);
  k_agg<<<N_NODES/4,256,0,stream>>>(hmid, offs, deg, src_s, w_s, Acat);
  k_gemm<<<gemmGrid,256,0,stream>>>(Acat, Wt, bias2, out, nullptr, N_NODES, 0);
}